// Round 12
// baseline (146.961 us; speedup 1.0000x reference)
//
#include <hip/hip_runtime.h>
#include <hip/hip_bf16.h>
#include <cstdint>
#include <cstddef>

// Problem constants (B=4, N=256, D=32, H=512)
#define NB 4
#define NN 256
#define DD 32
#define HH 512
#define FGRID 1024   // fused grid; blocks loop items bx, bx+FGRID, ...

typedef __attribute__((ext_vector_type(8))) short short8;    // 8 bf16 (4 VGPRs) — MFMA A/B frag
typedef __attribute__((ext_vector_type(4))) float f32x4;     // 16x16 C/D frag
typedef __attribute__((ext_vector_type(16))) float f32x16;   // 32x32 C/D frag

// HW packed fp32->bf16 (RNE). a -> low 16, b -> high 16.
static __device__ __forceinline__ unsigned cvtpk(float a, float b) {
  unsigned r;
  asm("v_cvt_pk_bf16_f32 %0, %1, %2" : "=v"(r) : "v"(a), "v"(b));
  return r;
}
static __device__ __forceinline__ unsigned short f2bf1(float a) {
  return (unsigned short)(cvtpk(a, 0.f) & 0xffffu);
}

// build a bf16 A/B frag from 8 consecutive fp32 (two float4 loads already done)
static __device__ __forceinline__ short8 pack8(float4 a0, float4 a1) {
  union { unsigned u[4]; short8 s; } r;
  r.u[0] = cvtpk(a0.x, a0.y); r.u[1] = cvtpk(a0.z, a0.w);
  r.u[2] = cvtpk(a1.x, a1.y); r.u[3] = cvtpk(a1.z, a1.w);
  return r.s;
}

// T4-style barrier: drain ONLY LDS ops (inter-wave communication), keep
// global B-prefetch loads in flight across the barrier. sched_barrier(0)
// pins the drain in place (guide rule #18: hipcc may hoist register-only
// ops past inline-asm waitcnt). Data-dependent vmcnt waits for the global
// loads are still compiler-inserted at the point of register consumption.
#define BAR() do { asm volatile("s_waitcnt lgkmcnt(0)" ::: "memory"); \
                   __builtin_amdgcn_sched_barrier(0);                 \
                   __builtin_amdgcn_s_barrier(); } while (0)

// ---------------------------------------------------------------------------
// prep0 (grid 64x256): build W1F — W1 in bf16 B-fragment layout (see R4).
// ---------------------------------------------------------------------------
__global__ __launch_bounds__(256) void prep0(const float* __restrict__ W1,
                                             unsigned short* __restrict__ W1F) {
  const int f = blockIdx.x * 256 + threadIdx.x;   // 16384 threads, 4 rows each
  #pragma unroll
  for (int r = 0; r < 4; ++r) {
    int row = r * 16384 + f;
    int lane = row & 63;
    int nt = (row >> 6) & 7, w2 = (row >> 9) & 3, nblk = row >> 11;
    int quad = lane >> 4, l16 = lane & 15;
    int nl = w2 * 128 + l16 * 8 + nt;
    int hl = nl >> 5, c = nl & 31;
    const float* src = W1 + (size_t)(nblk * 16 + hl);
    float v[8];
    #pragma unroll
    for (int e = 0; e < 8; ++e)
      v[e] = src[(size_t)((quad * 8 + e) * 32 + c) * 512];
    uint4 p;
    p.x = cvtpk(v[0], v[1]); p.y = cvtpk(v[2], v[3]);
    p.z = cvtpk(v[4], v[5]); p.w = cvtpk(v[6], v[7]);
    *(uint4*)&W1F[(size_t)row * 8] = p;
  }
}

// ---------------------------------------------------------------------------
// prep1 (grid 641x256): T-GEMM from W1F / W2F builder / queue build / fill.
// (unchanged from R4 — proven)
// ---------------------------------------------------------------------------
__global__ __launch_bounds__(256) void prep1(const float* __restrict__ z,
                                             const unsigned short* __restrict__ W1F,
                                             const float* __restrict__ W2,
                                             const float* __restrict__ motif,
                                             unsigned short* __restrict__ W2F,
                                             unsigned short* __restrict__ Tall,
                                             int* __restrict__ jlist,
                                             int* __restrict__ jcnt,
                                             int* __restrict__ wq,
                                             int* __restrict__ wqn,
                                             float* __restrict__ out) {
  const int blk = blockIdx.x;
  const int tid = threadIdx.x;
  if (blk < 512) {
    const int nblk = blk >> 4, mgrp = blk & 15;
    const int bibase = mgrp * 64;
    const int w2 = tid >> 6, lane = tid & 63;
    const int quad = lane >> 4, l16 = lane & 15;

    short8 bfr[8];
    #pragma unroll
    for (int nt = 0; nt < 8; ++nt)
      bfr[nt] = *(const short8*)&W1F[(size_t)((((nblk * 4 + w2) * 8) + nt) * 64 + lane) * 8];

    const int ncol = nblk * 512 + w2 * 128 + l16 * 8;
    #pragma unroll
    for (int mtg = 0; mtg < 2; ++mtg) {
      short8 afr[2];
      #pragma unroll
      for (int mi = 0; mi < 2; ++mi) {
        const float* zr = z + (size_t)(bibase + (mtg * 2 + mi) * 16 + l16) * 32 + quad * 8;
        float4 a0 = *(const float4*)(zr);
        float4 a1 = *(const float4*)(zr + 4);
        afr[mi] = pack8(a0, a1);
      }
      f32x4 d[2][8];
      #pragma unroll
      for (int mi = 0; mi < 2; ++mi)
        #pragma unroll
        for (int nt = 0; nt < 8; ++nt)
          d[mi][nt] = __builtin_amdgcn_mfma_f32_16x16x32_bf16(
              afr[mi], bfr[nt], (f32x4){0.f, 0.f, 0.f, 0.f}, 0, 0, 0);
      #pragma unroll
      for (int mi = 0; mi < 2; ++mi)
        #pragma unroll
        for (int r = 0; r < 4; ++r) {
          int rowbi = bibase + (mtg * 2 + mi) * 16 + quad * 4 + r;
          if (motif[rowbi] != 0.f) {        // masked rows never read by fused
            uint4 p;
            p.x = cvtpk(d[mi][0][r], d[mi][1][r]);
            p.y = cvtpk(d[mi][2][r], d[mi][3][r]);
            p.z = cvtpk(d[mi][4][r], d[mi][5][r]);
            p.w = cvtpk(d[mi][6][r], d[mi][7][r]);
            *(uint4*)&Tall[(size_t)rowbi * 16384 + ncol] = p;
          }
        }
    }
  } else if (blk < 576) {
    int f8 = (blk - 512) * 256 + tid;       // frag-slot index (8 elems each)
    int lane = f8 & 63;
    int nt = (f8 >> 6) & 1, s = (f8 >> 7) & 3, hc = (f8 >> 9) & 7, w = (f8 >> 12) & 3;
    int k2 = w * 64 + nt * 32 + (lane & 31);
    int hb = hc * 64 + s * 16 + (lane >> 5) * 8;
    float v[8];
    #pragma unroll
    for (int e = 0; e < 8; ++e) v[e] = W2[(hb + e) * 256 + k2];
    uint4 p;
    p.x = cvtpk(v[0], v[1]); p.y = cvtpk(v[2], v[3]);
    p.z = cvtpk(v[4], v[5]); p.w = cvtpk(v[6], v[7]);
    ((uint4*)W2F)[f8] = p;
  } else if (blk == 576) {
    // ---- compaction + queue build: wave w handles batch b = w
    __shared__ int itemc[4];
    __shared__ int baseh[4];
    const int w = tid >> 6, lane = tid & 63;
    int cnt = 0;
    if (w < NB) {
      #pragma unroll
      for (int ch = 0; ch < 4; ++ch) {
        int j = ch * 64 + lane;
        float m = motif[w * 256 + j];
        bool alive = (m != 0.f);
        unsigned long long mk = __ballot(alive);
        unsigned long long below = mk & ((1ull << lane) - 1ull);
        int pos = __popcll(below);
        if (alive) jlist[w * 256 + cnt + pos] = j;
        cnt += __popcll(mk);
      }
      if (lane == 0) {
        jcnt[w] = cnt;
        itemc[w] = cnt * ((cnt + 63) >> 6);
      }
    }
    __syncthreads();
    if (tid == 0) {
      int s = 0;
      #pragma unroll
      for (int k = 0; k < NB; ++k) { baseh[k] = s; s += itemc[k]; }
      *wqn = s;
    }
    __syncthreads();
    if (w < NB) {
      const int K = (cnt + 63) >> 6;
      const int base = baseh[w];
      const int L2n = cnt * K;
      int rank = 0;
      #pragma unroll
      for (int ch = 0; ch < 4; ++ch) {
        int i = ch * 64 + lane;
        bool alive = (motif[w * 256 + i] != 0.f);
        unsigned long long mk = __ballot(alive);
        unsigned long long below = mk & ((1ull << lane) - 1ull);
        int pos = __popcll(below);
        if (alive) {
          int idx0 = (rank + pos) * K;
          for (int jt = 0; jt < K; ++jt) {
            int idx = idx0 + jt;
            int nidx = idx;
            // XCD pair-locality: place the two items of one bi 8 apart so
            // round-robin block->XCD puts them on the same XCD.
            if (K == 2) {
              int g = idx >> 4;
              if (g * 16 + 16 <= L2n)
                nidx = g * 16 + ((idx & 1) << 3) + ((idx >> 1) & 7);
            }
            wq[base + nidx] = (w * 256 + i) * 4 + jt;
          }
        }
        rank += __popcll(mk);
      }
    }
  } else {
    // ---- fill duty: constants for masked (bi,j) pairs; 64 blocks x 4096
    const size_t OUT2 = (size_t)NB * NN * NN;
    const int c = blk - 577;
    for (int p = c * 4096 + tid; p < (c + 1) * 4096; p += 256) {
      int bi = p >> 8, j = p & 255, b = bi >> 8;
      if (motif[bi] == 0.f || motif[b * 256 + j] == 0.f) {
        out[p] = 0.5f;
        out[OUT2 + p] = 0.f;
      }
    }
  }
}

// ---------------------------------------------------------------------------
// fused (round 12 = round 11 resubmit; R11 bench was a container flake):
//  (1) T4 counted-drain barriers: lgkmcnt(0)-only + sched_barrier(0) before
//      raw s_barrier — B-prefetch globals stay in flight across all 5
//      barriers/item (compiler's __syncthreads vmcnt(0) drain was pure
//      overhead: bfp loads land in the consuming wave's own regs).
//  (2) grid 1024 + per-block item loop: removes 3072 null-block dispatches;
//      phase-3's B-prefetch wraps to quarter 0 so bfp stays warm across items.
// No launch_bounds cap (R2/R5: caps spill).
// ---------------------------------------------------------------------------
__global__ __launch_bounds__(256) void fused(const unsigned short* __restrict__ Tall,
                                             const unsigned short* __restrict__ W2F,
                                             const float* __restrict__ z,
                                             const float* __restrict__ b1,
                                             const float* __restrict__ b2,
                                             const float* __restrict__ W3,
                                             const float* __restrict__ b3,
                                             const float* __restrict__ motif,
                                             const int* __restrict__ jlist,
                                             const int* __restrict__ jcnt,
                                             const int* __restrict__ wq,
                                             const int* __restrict__ wqn,
                                             float* __restrict__ out) {
  __shared__ unsigned short h1s[2][64 * 136];  // ping-pong quarter buffers (34.8 KB)
  __shared__ float red[256];

  const int bx = blockIdx.x;
  const int tid = threadIdx.x;
  const size_t OUT2 = (size_t)NB * NN * NN;
  const int nq = *wqn;

  if (bx >= nq) return;                      // fill handled by prep1

  const int w = tid >> 6, lane = tid & 63;
  const int quad = lane >> 4, l16 = lane & 15;
  const int L = lane >> 5, c32 = lane & 31;

  const unsigned short* Wp = W2F + w * 32768 + lane * 8;
  const float* b1base = b1 + w * 16 + quad * 4;

  // epilogue constants: this wave owns k2 in [64w, 64w+64)  (item-independent)
  float b2v[2], w3v[2];
  #pragma unroll
  for (int nt = 0; nt < 2; ++nt) {
    int k2 = w * 64 + nt * 32 + c32;
    b2v[nt] = b2[k2];
    w3v[nt] = W3[k2];
  }
  const float b3s = b3[0];

  // ---- B init: quarter-0 rows 0..7 (steady across items via phase-3 wrap)
  short8 bfp[8][2];
  #pragma unroll
  for (int p = 0; p < 8; ++p) {
    bfp[p][0] = *(const short8*)(Wp + p * 1024);
    bfp[p][1] = *(const short8*)(Wp + p * 1024 + 512);
  }

  #pragma unroll 1
  for (int it = bx; it < nq; it += FGRID) {
    const int item = wq[it];
    const int bi = item >> 2, jt = item & 3;
    const int b = bi >> 8;
    const int cnt = jcnt[b];
    const int slotbase = jt * 64;
    const float mi_v = motif[bi];

    const unsigned short* Tbase = Tall + (size_t)bi * 16384 + (w * 16 + l16) * 32 + quad * 8;

    // phase-1 z frags gathered through jlist
    short8 zfr[4];
    #pragma unroll
    for (int sg = 0; sg < 4; ++sg) {
      int slot = slotbase + sg * 16 + l16;
      int sc = slot < cnt ? slot : cnt - 1;
      int jj = jlist[b * 256 + sc] & 255;
      const float* zr = z + (size_t)(b * 256 + jj) * 32 + quad * 8;
      float4 a0 = *(const float4*)(zr);
      float4 a1 = *(const float4*)(zr + 4);
      zfr[sg] = pack8(a0, a1);
    }

    f32x16 acc[2][2];
    #pragma unroll
    for (int mt = 0; mt < 2; ++mt)
      #pragma unroll
      for (int nt = 0; nt < 2; ++nt)
        acc[mt][nt] = (f32x16){0.f,0.f,0.f,0.f,0.f,0.f,0.f,0.f,
                               0.f,0.f,0.f,0.f,0.f,0.f,0.f,0.f};

    // ---- P1(quarter 0) -> buf0   (qq = 0,1)
    #pragma unroll
    for (int qq = 0; qq < 2; ++qq) {
      short8 tfr = *(const short8*)(Tbase + qq * 2048);
      float4 b1f = *(const float4*)(b1base + qq * 64);
      f32x4 cin = {b1f.x, b1f.y, b1f.z, b1f.w};
      #pragma unroll
      for (int sg = 0; sg < 4; ++sg) {
        f32x4 d = __builtin_amdgcn_mfma_f32_16x16x32_bf16(tfr, zfr[sg], cin, 0, 0, 0);
        uint2 p;
        p.x = cvtpk(fmaxf(d[0], 0.f), fmaxf(d[1], 0.f));
        p.y = cvtpk(fmaxf(d[2], 0.f), fmaxf(d[3], 0.f));
        *(uint2*)&h1s[0][(sg * 16 + l16) * 136 + qq * 64 + w * 16 + quad * 4] = p;
      }
    }
    BAR();

    // ---- 4 overlapped phases: P1(q+1) || P2(q)
    #pragma unroll
    for (int q = 0; q < 4; ++q) {
      // P1(q+1) -> buf[(q+1)&1]  (qq = 2q+2, 2q+3)
      if (q < 3) {
        #pragma unroll
        for (int qi = 0; qi < 2; ++qi) {
          const int qq = 2 * q + 2 + qi;
          short8 tfr = *(const short8*)(Tbase + qq * 2048);
          float4 b1f = *(const float4*)(b1base + qq * 64);
          f32x4 cin = {b1f.x, b1f.y, b1f.z, b1f.w};
          #pragma unroll
          for (int sg = 0; sg < 4; ++sg) {
            f32x4 d = __builtin_amdgcn_mfma_f32_16x16x32_bf16(tfr, zfr[sg], cin, 0, 0, 0);
            uint2 p;
            p.x = cvtpk(fmaxf(d[0], 0.f), fmaxf(d[1], 0.f));
            p.y = cvtpk(fmaxf(d[2], 0.f), fmaxf(d[3], 0.f));
            *(uint2*)&h1s[(q + 1) & 1][(sg * 16 + l16) * 136 + qi * 64 + w * 16 + quad * 4] = p;
          }
        }
      }
      // P2(q) from buf[q&1]; consume bfp[u], prefetch next quarter's row u
      // (q==3 wraps to quarter 0 for the NEXT item -> bfp always warm)
      {
        const unsigned short* h1r = &h1s[q & 1][c32 * 136 + L * 8];
        short8 afp[2][2];
        afp[0][0] = *(const short8*)(h1r);
        afp[0][1] = *(const short8*)(h1r + 32 * 136);
        afp[1][0] = *(const short8*)(h1r + 16);
        afp[1][1] = *(const short8*)(h1r + 32 * 136 + 16);
        #pragma unroll
        for (int u = 0; u < 8; ++u) {
          const int cur = u & 1;
          short8 a0 = afp[cur][0], a1 = afp[cur][1];
          short8 b0 = bfp[u][0], b1q = bfp[u][1];
          if (u < 6) {
            afp[cur][0] = *(const short8*)(h1r + (u + 2) * 16);
            afp[cur][1] = *(const short8*)(h1r + 32 * 136 + (u + 2) * 16);
          }
          {
            const int nqt = (q + 1) & 3;    // next quarter (wraps to 0)
            const unsigned short* Wn = Wp + (nqt >> 1) * 16384
                                          + (8 * (nqt & 1) + u) * 1024;
            bfp[u][0] = *(const short8*)(Wn);
            bfp[u][1] = *(const short8*)(Wn + 512);
          }
          acc[0][0] = __builtin_amdgcn_mfma_f32_32x32x16_bf16(a0, b0, acc[0][0], 0, 0, 0);
          acc[0][1] = __builtin_amdgcn_mfma_f32_32x32x16_bf16(a0, b1q, acc[0][1], 0, 0, 0);
          acc[1][0] = __builtin_amdgcn_mfma_f32_32x32x16_bf16(a1, b0, acc[1][0], 0, 0, 0);
          acc[1][1] = __builtin_amdgcn_mfma_f32_32x32x16_bf16(a1, b1q, acc[1][1], 0, 0, 0);
        }
      }
      // epilogue folded into the last phase (before its barrier)
      if (q == 3) {
        float pr[2][16];
        #pragma unroll
        for (int mt = 0; mt < 2; ++mt)
          #pragma unroll
          for (int reg = 0; reg < 16; ++reg) {
            float s = 0.f;
            #pragma unroll
            for (int nt = 0; nt < 2; ++nt) {
              float v = acc[mt][nt][reg] + b2v[nt];
              v = v > 0.f ? v : 0.f;
              s += v * w3v[nt];
            }
            s += __shfl_xor(s, 1);
            s += __shfl_xor(s, 2);
            s += __shfl_xor(s, 4);
            s += __shfl_xor(s, 8);
            s += __shfl_xor(s, 16);
            pr[mt][reg] = s;
          }
        if (c32 == 0) {
          #pragma unroll
          for (int mt = 0; mt < 2; ++mt)
            #pragma unroll
            for (int g = 0; g < 4; ++g) {
              float4 vv = {pr[mt][g * 4 + 0], pr[mt][g * 4 + 1],
                           pr[mt][g * 4 + 2], pr[mt][g * 4 + 3]};
              *(float4*)&red[w * 64 + mt * 32 + g * 8 + L * 4] = vv;
            }
        }
      }
      BAR();
    }

    // ---- readout (next item's prologue overlaps via other waves)
    if (tid < 64) {
      int slot = slotbase + tid;
      if (slot < cnt) {
        int j = jlist[b * 256 + slot] & 255;
        float logit = red[tid] + red[64 + tid] + red[128 + tid] + red[192 + tid] + b3s;
        float mm = mi_v * motif[b * 256 + j];
        logit *= mm;
        float map = 1.f / (1.f + expf(-logit));
        size_t idx = (size_t)bi * 256 + j;
        out[idx] = map;
        out[OUT2 + idx] = logit;
      }
    }
  }
}

// ---------------------------------------------------------------------------
extern "C" void kernel_launch(void* const* d_in, const int* in_sizes, int n_in,
                              void* d_out, int out_size, void* d_ws, size_t ws_size,
                              hipStream_t stream) {
  const float* z     = (const float*)d_in[0];
  const float* motif = (const float*)d_in[1];
  // d_in[2] residue_mask: all-ones, unused by the reference computation
  const float* W1 = (const float*)d_in[3];
  const float* b1 = (const float*)d_in[4];
  const float* W2 = (const float*)d_in[5];
  const float* b2 = (const float*)d_in[6];
  const float* W3 = (const float*)d_in[7];
  const float* b3 = (const float*)d_in[8];
  float* out = (float*)d_out;

  char* ws = (char*)d_ws;
  unsigned short* Tall = (unsigned short*)ws;                            // 32 MiB
  unsigned short* W2F  = (unsigned short*)(ws + 33554432);               // 256 KiB
  unsigned short* W1F  = (unsigned short*)(ws + 33554432 + 262144);      // 1 MiB
  char* tail = ws + 33554432 + 262144 + 1048576;
  int* jlist = (int*)(tail);                                             // 4 KiB
  int* jcnt  = (int*)(tail + 4096);                                      // 64 B
  int* wq    = (int*)(tail + 4096 + 64);                                 // 16 KiB
  int* wqn   = (int*)(tail + 4096 + 64 + 16384);                         // 64 B

  prep0<<<64, 256, 0, stream>>>(W1, W1F);
  prep1<<<641, 256, 0, stream>>>(z, W1F, W2, motif, W2F, Tall,
                                 jlist, jcnt, wq, wqn, out);
  fused<<<FGRID, 256, 0, stream>>>(Tall, W2F, z, b1, b2, W3, b3, motif,
                                   jlist, jcnt, wq, wqn, out);
}

// Round 13
// 122.794 us; speedup vs baseline: 1.1968x; 1.1968x over previous
//
#include <hip/hip_runtime.h>
#include <hip/hip_bf16.h>
#include <cstdint>
#include <cstddef>

// Problem constants (B=4, N=256, D=32, H=512)
#define NB 4
#define NN 256
#define DD 32
#define HH 512

typedef __attribute__((ext_vector_type(8))) short short8;    // 8 bf16 (4 VGPRs) — MFMA A/B frag
typedef __attribute__((ext_vector_type(4))) float f32x4;     // 16x16 C/D frag
typedef __attribute__((ext_vector_type(16))) float f32x16;   // 32x32 C/D frag

// HW packed fp32->bf16 (RNE). a -> low 16, b -> high 16.
static __device__ __forceinline__ unsigned cvtpk(float a, float b) {
  unsigned r;
  asm("v_cvt_pk_bf16_f32 %0, %1, %2" : "=v"(r) : "v"(a), "v"(b));
  return r;
}
static __device__ __forceinline__ unsigned short f2bf1(float a) {
  return (unsigned short)(cvtpk(a, 0.f) & 0xffffu);
}

// build a bf16 A/B frag from 8 consecutive fp32 (two float4 loads already done)
static __device__ __forceinline__ short8 pack8(float4 a0, float4 a1) {
  union { unsigned u[4]; short8 s; } r;
  r.u[0] = cvtpk(a0.x, a0.y); r.u[1] = cvtpk(a0.z, a0.w);
  r.u[2] = cvtpk(a1.x, a1.y); r.u[3] = cvtpk(a1.z, a1.w);
  return r.s;
}

// T4-style barrier: drain ONLY LDS ops (the inter-wave communication path),
// keep global B-prefetch loads in flight across the barrier. __syncthreads()
// would emit s_waitcnt vmcnt(0) lgkmcnt(0), flushing ~16 in-flight globals
// at every barrier (5x/item) for no correctness benefit — bfp loads land in
// the consuming wave's own registers and get data-dependent vmcnt waits at
// use. The "memory" clobber orders all compiler-visible memory ops (incl.
// LDS reads/writes) across this point, so no sched_barrier is needed
// (R12 showed sched_barrier+item-loop perturbs regalloc badly).
#define BAR() do { asm volatile("s_waitcnt lgkmcnt(0)" ::: "memory"); \
                   __builtin_amdgcn_s_barrier(); } while (0)

// ---------------------------------------------------------------------------
// prep0 (grid 64x256): build W1F — W1 in bf16 B-fragment layout (see R4).
// ---------------------------------------------------------------------------
__global__ __launch_bounds__(256) void prep0(const float* __restrict__ W1,
                                             unsigned short* __restrict__ W1F) {
  const int f = blockIdx.x * 256 + threadIdx.x;   // 16384 threads, 4 rows each
  #pragma unroll
  for (int r = 0; r < 4; ++r) {
    int row = r * 16384 + f;
    int lane = row & 63;
    int nt = (row >> 6) & 7, w2 = (row >> 9) & 3, nblk = row >> 11;
    int quad = lane >> 4, l16 = lane & 15;
    int nl = w2 * 128 + l16 * 8 + nt;
    int hl = nl >> 5, c = nl & 31;
    const float* src = W1 + (size_t)(nblk * 16 + hl);
    float v[8];
    #pragma unroll
    for (int e = 0; e < 8; ++e)
      v[e] = src[(size_t)((quad * 8 + e) * 32 + c) * 512];
    uint4 p;
    p.x = cvtpk(v[0], v[1]); p.y = cvtpk(v[2], v[3]);
    p.z = cvtpk(v[4], v[5]); p.w = cvtpk(v[6], v[7]);
    *(uint4*)&W1F[(size_t)row * 8] = p;
  }
}

// ---------------------------------------------------------------------------
// prep1 (grid 641x256): T-GEMM from W1F / W2F builder / queue build / fill.
// (unchanged from R4 — proven)
// ---------------------------------------------------------------------------
__global__ __launch_bounds__(256) void prep1(const float* __restrict__ z,
                                             const unsigned short* __restrict__ W1F,
                                             const float* __restrict__ W2,
                                             const float* __restrict__ motif,
                                             unsigned short* __restrict__ W2F,
                                             unsigned short* __restrict__ Tall,
                                             int* __restrict__ jlist,
                                             int* __restrict__ jcnt,
                                             int* __restrict__ wq,
                                             int* __restrict__ wqn,
                                             float* __restrict__ out) {
  const int blk = blockIdx.x;
  const int tid = threadIdx.x;
  if (blk < 512) {
    const int nblk = blk >> 4, mgrp = blk & 15;
    const int bibase = mgrp * 64;
    const int w2 = tid >> 6, lane = tid & 63;
    const int quad = lane >> 4, l16 = lane & 15;

    short8 bfr[8];
    #pragma unroll
    for (int nt = 0; nt < 8; ++nt)
      bfr[nt] = *(const short8*)&W1F[(size_t)((((nblk * 4 + w2) * 8) + nt) * 64 + lane) * 8];

    const int ncol = nblk * 512 + w2 * 128 + l16 * 8;
    #pragma unroll
    for (int mtg = 0; mtg < 2; ++mtg) {
      short8 afr[2];
      #pragma unroll
      for (int mi = 0; mi < 2; ++mi) {
        const float* zr = z + (size_t)(bibase + (mtg * 2 + mi) * 16 + l16) * 32 + quad * 8;
        float4 a0 = *(const float4*)(zr);
        float4 a1 = *(const float4*)(zr + 4);
        afr[mi] = pack8(a0, a1);
      }
      f32x4 d[2][8];
      #pragma unroll
      for (int mi = 0; mi < 2; ++mi)
        #pragma unroll
        for (int nt = 0; nt < 8; ++nt)
          d[mi][nt] = __builtin_amdgcn_mfma_f32_16x16x32_bf16(
              afr[mi], bfr[nt], (f32x4){0.f, 0.f, 0.f, 0.f}, 0, 0, 0);
      #pragma unroll
      for (int mi = 0; mi < 2; ++mi)
        #pragma unroll
        for (int r = 0; r < 4; ++r) {
          int rowbi = bibase + (mtg * 2 + mi) * 16 + quad * 4 + r;
          if (motif[rowbi] != 0.f) {        // masked rows never read by fused
            uint4 p;
            p.x = cvtpk(d[mi][0][r], d[mi][1][r]);
            p.y = cvtpk(d[mi][2][r], d[mi][3][r]);
            p.z = cvtpk(d[mi][4][r], d[mi][5][r]);
            p.w = cvtpk(d[mi][6][r], d[mi][7][r]);
            *(uint4*)&Tall[(size_t)rowbi * 16384 + ncol] = p;
          }
        }
    }
  } else if (blk < 576) {
    int f8 = (blk - 512) * 256 + tid;       // frag-slot index (8 elems each)
    int lane = f8 & 63;
    int nt = (f8 >> 6) & 1, s = (f8 >> 7) & 3, hc = (f8 >> 9) & 7, w = (f8 >> 12) & 3;
    int k2 = w * 64 + nt * 32 + (lane & 31);
    int hb = hc * 64 + s * 16 + (lane >> 5) * 8;
    float v[8];
    #pragma unroll
    for (int e = 0; e < 8; ++e) v[e] = W2[(hb + e) * 256 + k2];
    uint4 p;
    p.x = cvtpk(v[0], v[1]); p.y = cvtpk(v[2], v[3]);
    p.z = cvtpk(v[4], v[5]); p.w = cvtpk(v[6], v[7]);
    ((uint4*)W2F)[f8] = p;
  } else if (blk == 576) {
    // ---- compaction + queue build: wave w handles batch b = w
    __shared__ int itemc[4];
    __shared__ int baseh[4];
    const int w = tid >> 6, lane = tid & 63;
    int cnt = 0;
    if (w < NB) {
      #pragma unroll
      for (int ch = 0; ch < 4; ++ch) {
        int j = ch * 64 + lane;
        float m = motif[w * 256 + j];
        bool alive = (m != 0.f);
        unsigned long long mk = __ballot(alive);
        unsigned long long below = mk & ((1ull << lane) - 1ull);
        int pos = __popcll(below);
        if (alive) jlist[w * 256 + cnt + pos] = j;
        cnt += __popcll(mk);
      }
      if (lane == 0) {
        jcnt[w] = cnt;
        itemc[w] = cnt * ((cnt + 63) >> 6);
      }
    }
    __syncthreads();
    if (tid == 0) {
      int s = 0;
      #pragma unroll
      for (int k = 0; k < NB; ++k) { baseh[k] = s; s += itemc[k]; }
      *wqn = s;
    }
    __syncthreads();
    if (w < NB) {
      const int K = (cnt + 63) >> 6;
      const int base = baseh[w];
      const int L2n = cnt * K;
      int rank = 0;
      #pragma unroll
      for (int ch = 0; ch < 4; ++ch) {
        int i = ch * 64 + lane;
        bool alive = (motif[w * 256 + i] != 0.f);
        unsigned long long mk = __ballot(alive);
        unsigned long long below = mk & ((1ull << lane) - 1ull);
        int pos = __popcll(below);
        if (alive) {
          int idx0 = (rank + pos) * K;
          for (int jt = 0; jt < K; ++jt) {
            int idx = idx0 + jt;
            int nidx = idx;
            // XCD pair-locality: place the two items of one bi 8 apart so
            // round-robin block->XCD puts them on the same XCD.
            if (K == 2) {
              int g = idx >> 4;
              if (g * 16 + 16 <= L2n)
                nidx = g * 16 + ((idx & 1) << 3) + ((idx >> 1) & 7);
            }
            wq[base + nidx] = (w * 256 + i) * 4 + jt;
          }
        }
        rank += __popcll(mk);
      }
    }
  } else {
    // ---- fill duty: constants for masked (bi,j) pairs; 64 blocks x 4096
    const size_t OUT2 = (size_t)NB * NN * NN;
    const int c = blk - 577;
    for (int p = c * 4096 + tid; p < (c + 1) * 4096; p += 256) {
      int bi = p >> 8, j = p & 255, b = bi >> 8;
      if (motif[bi] == 0.f || motif[b * 256 + j] == 0.f) {
        out[p] = 0.5f;
        out[OUT2 + p] = 0.f;
      }
    }
  }
}

// ---------------------------------------------------------------------------
// fused (round 13): EXACT R10 champion body (43.9 us, VGPR 104, grid 4096,
// single item per block — R9/R12 proved item loops balloon regalloc) with
// ONE change: all 5 __syncthreads() -> BAR() (lgkmcnt(0)-only drain + raw
// s_barrier), so the in-flight B-prefetch globals survive the barriers.
// Clean A/B of the counted-drain lever in isolation.
// ---------------------------------------------------------------------------
__global__ __launch_bounds__(256) void fused(const unsigned short* __restrict__ Tall,
                                             const unsigned short* __restrict__ W2F,
                                             const float* __restrict__ z,
                                             const float* __restrict__ b1,
                                             const float* __restrict__ b2,
                                             const float* __restrict__ W3,
                                             const float* __restrict__ b3,
                                             const float* __restrict__ motif,
                                             const int* __restrict__ jlist,
                                             const int* __restrict__ jcnt,
                                             const int* __restrict__ wq,
                                             const int* __restrict__ wqn,
                                             float* __restrict__ out) {
  __shared__ unsigned short h1s[2][64 * 136];  // ping-pong quarter buffers (34.8 KB)
  __shared__ float red[256];

  const int bx = blockIdx.x;
  const int tid = threadIdx.x;
  const size_t OUT2 = (size_t)NB * NN * NN;
  const int nq = *wqn;

  if (bx >= nq) return;                      // fill handled by prep1
  const int item = wq[bx];

  const int w = tid >> 6, lane = tid & 63;
  const int quad = lane >> 4, l16 = lane & 15;
  const int L = lane >> 5, c32 = lane & 31;

  const int bi = item >> 2, jt = item & 3;
  const int b = bi >> 8;
  const int cnt = jcnt[b];
  const int slotbase = jt * 64;
  const float mi_v = motif[bi];

  const unsigned short* Tbase = Tall + (size_t)bi * 16384 + (w * 16 + l16) * 32 + quad * 8;
  const unsigned short* Wp = W2F + w * 32768 + lane * 8;
  const float* b1base = b1 + w * 16 + quad * 4;

  // ---- hoisted B init: quarter-0 rows 0..7, in flight under startup
  short8 bfp[8][2];
  #pragma unroll
  for (int p = 0; p < 8; ++p) {
    bfp[p][0] = *(const short8*)(Wp + p * 1024);
    bfp[p][1] = *(const short8*)(Wp + p * 1024 + 512);
  }

  // phase-1 z frags gathered through jlist
  short8 zfr[4];
  #pragma unroll
  for (int sg = 0; sg < 4; ++sg) {
    int slot = slotbase + sg * 16 + l16;
    int sc = slot < cnt ? slot : cnt - 1;
    int jj = jlist[b * 256 + sc] & 255;
    const float* zr = z + (size_t)(b * 256 + jj) * 32 + quad * 8;
    float4 a0 = *(const float4*)(zr);
    float4 a1 = *(const float4*)(zr + 4);
    zfr[sg] = pack8(a0, a1);
  }

  // epilogue constants: this wave owns k2 in [64w, 64w+64)
  float b2v[2], w3v[2];
  #pragma unroll
  for (int nt = 0; nt < 2; ++nt) {
    int k2 = w * 64 + nt * 32 + c32;
    b2v[nt] = b2[k2];
    w3v[nt] = W3[k2];
  }

  f32x16 acc[2][2];
  #pragma unroll
  for (int mt = 0; mt < 2; ++mt)
    #pragma unroll
    for (int nt = 0; nt < 2; ++nt)
      acc[mt][nt] = (f32x16){0.f,0.f,0.f,0.f,0.f,0.f,0.f,0.f,
                             0.f,0.f,0.f,0.f,0.f,0.f,0.f,0.f};

  // ---- P1(quarter 0) -> buf0   (qq = 0,1)
  #pragma unroll
  for (int qq = 0; qq < 2; ++qq) {
    short8 tfr = *(const short8*)(Tbase + qq * 2048);
    float4 b1f = *(const float4*)(b1base + qq * 64);
    f32x4 cin = {b1f.x, b1f.y, b1f.z, b1f.w};
    #pragma unroll
    for (int sg = 0; sg < 4; ++sg) {
      f32x4 d = __builtin_amdgcn_mfma_f32_16x16x32_bf16(tfr, zfr[sg], cin, 0, 0, 0);
      uint2 p;
      p.x = cvtpk(fmaxf(d[0], 0.f), fmaxf(d[1], 0.f));
      p.y = cvtpk(fmaxf(d[2], 0.f), fmaxf(d[3], 0.f));
      *(uint2*)&h1s[0][(sg * 16 + l16) * 136 + qq * 64 + w * 16 + quad * 4] = p;
    }
  }
  BAR();

  // ---- 4 overlapped phases: P1(q+1) || P2(q)
  #pragma unroll
  for (int q = 0; q < 4; ++q) {
    // P1(q+1) -> buf[(q+1)&1]  (qq = 2q+2, 2q+3)
    if (q < 3) {
      #pragma unroll
      for (int qi = 0; qi < 2; ++qi) {
        const int qq = 2 * q + 2 + qi;
        short8 tfr = *(const short8*)(Tbase + qq * 2048);
        float4 b1f = *(const float4*)(b1base + qq * 64);
        f32x4 cin = {b1f.x, b1f.y, b1f.z, b1f.w};
        #pragma unroll
        for (int sg = 0; sg < 4; ++sg) {
          f32x4 d = __builtin_amdgcn_mfma_f32_16x16x32_bf16(tfr, zfr[sg], cin, 0, 0, 0);
          uint2 p;
          p.x = cvtpk(fmaxf(d[0], 0.f), fmaxf(d[1], 0.f));
          p.y = cvtpk(fmaxf(d[2], 0.f), fmaxf(d[3], 0.f));
          *(uint2*)&h1s[(q + 1) & 1][(sg * 16 + l16) * 136 + qi * 64 + w * 16 + quad * 4] = p;
        }
      }
    }
    // P2(q) from buf[q&1]; consume bfp[u], prefetch next quarter's row u
    {
      const unsigned short* h1r = &h1s[q & 1][c32 * 136 + L * 8];
      short8 afp[2][2];
      afp[0][0] = *(const short8*)(h1r);
      afp[0][1] = *(const short8*)(h1r + 32 * 136);
      afp[1][0] = *(const short8*)(h1r + 16);
      afp[1][1] = *(const short8*)(h1r + 32 * 136 + 16);
      #pragma unroll
      for (int u = 0; u < 8; ++u) {
        const int cur = u & 1;
        short8 a0 = afp[cur][0], a1 = afp[cur][1];
        short8 b0 = bfp[u][0], b1q = bfp[u][1];
        if (u < 6) {
          afp[cur][0] = *(const short8*)(h1r + (u + 2) * 16);
          afp[cur][1] = *(const short8*)(h1r + 32 * 136 + (u + 2) * 16);
        }
        if (q < 3) {
          // next quarter nqt = q+1: half = nqt>>1, row = 8*(nqt&1)+u
          const unsigned short* Wn = Wp + ((q + 1) >> 1) * 16384
                                        + (8 * ((q + 1) & 1) + u) * 1024;
          bfp[u][0] = *(const short8*)(Wn);
          bfp[u][1] = *(const short8*)(Wn + 512);
        }
        acc[0][0] = __builtin_amdgcn_mfma_f32_32x32x16_bf16(a0, b0, acc[0][0], 0, 0, 0);
        acc[0][1] = __builtin_amdgcn_mfma_f32_32x32x16_bf16(a0, b1q, acc[0][1], 0, 0, 0);
        acc[1][0] = __builtin_amdgcn_mfma_f32_32x32x16_bf16(a1, b0, acc[1][0], 0, 0, 0);
        acc[1][1] = __builtin_amdgcn_mfma_f32_32x32x16_bf16(a1, b1q, acc[1][1], 0, 0, 0);
      }
    }
    // epilogue folded into the last phase (before its barrier)
    if (q == 3) {
      float pr[2][16];
      #pragma unroll
      for (int mt = 0; mt < 2; ++mt)
        #pragma unroll
        for (int reg = 0; reg < 16; ++reg) {
          float s = 0.f;
          #pragma unroll
          for (int nt = 0; nt < 2; ++nt) {
            float v = acc[mt][nt][reg] + b2v[nt];
            v = v > 0.f ? v : 0.f;
            s += v * w3v[nt];
          }
          s += __shfl_xor(s, 1);
          s += __shfl_xor(s, 2);
          s += __shfl_xor(s, 4);
          s += __shfl_xor(s, 8);
          s += __shfl_xor(s, 16);
          pr[mt][reg] = s;
        }
      if (c32 == 0) {
        #pragma unroll
        for (int mt = 0; mt < 2; ++mt)
          #pragma unroll
          for (int g = 0; g < 4; ++g) {
            float4 vv = {pr[mt][g * 4 + 0], pr[mt][g * 4 + 1],
                         pr[mt][g * 4 + 2], pr[mt][g * 4 + 3]};
            *(float4*)&red[w * 64 + mt * 32 + g * 8 + L * 4] = vv;
          }
      }
    }
    BAR();
  }

  // ---- readout
  if (tid < 64) {
    int slot = slotbase + tid;
    if (slot < cnt) {
      int j = jlist[b * 256 + slot] & 255;
      float logit = red[tid] + red[64 + tid] + red[128 + tid] + red[192 + tid] + b3[0];
      float mm = mi_v * motif[b * 256 + j];
      logit *= mm;
      float map = 1.f / (1.f + expf(-logit));
      size_t idx = (size_t)bi * 256 + j;
      out[idx] = map;
      out[OUT2 + idx] = logit;
    }
  }
}

// ---------------------------------------------------------------------------
extern "C" void kernel_launch(void* const* d_in, const int* in_sizes, int n_in,
                              void* d_out, int out_size, void* d_ws, size_t ws_size,
                              hipStream_t stream) {
  const float* z     = (const float*)d_in[0];
  const float* motif = (const float*)d_in[1];
  // d_in[2] residue_mask: all-ones, unused by the reference computation
  const float* W1 = (const float*)d_in[3];
  const float* b1 = (const float*)d_in[4];
  const float* W2 = (const float*)d_in[5];
  const float* b2 = (const float*)d_in[6];
  const float* W3 = (const float*)d_in[7];
  const float* b3 = (const float*)d_in[8];
  float* out = (float*)d_out;

  char* ws = (char*)d_ws;
  unsigned short* Tall = (unsigned short*)ws;                            // 32 MiB
  unsigned short* W2F  = (unsigned short*)(ws + 33554432);               // 256 KiB
  unsigned short* W1F  = (unsigned short*)(ws + 33554432 + 262144);      // 1 MiB
  char* tail = ws + 33554432 + 262144 + 1048576;
  int* jlist = (int*)(tail);                                             // 4 KiB
  int* jcnt  = (int*)(tail + 4096);                                      // 64 B
  int* wq    = (int*)(tail + 4096 + 64);                                 // 16 KiB
  int* wqn   = (int*)(tail + 4096 + 64 + 16384);                         // 64 B

  prep0<<<64, 256, 0, stream>>>(W1, W1F);
  prep1<<<641, 256, 0, stream>>>(z, W1F, W2, motif, W2F, Tall,
                                 jlist, jcnt, wq, wqn, out);
  fused<<<4096, 256, 0, stream>>>(Tall, W2F, z, b1, b2, W3, b3, motif,
                                  jlist, jcnt, wq, wqn, out);
}

// Round 14
// 121.480 us; speedup vs baseline: 1.2098x; 1.0108x over previous
//
#include <hip/hip_runtime.h>
#include <hip/hip_bf16.h>
#include <cstdint>
#include <cstddef>

// Problem constants (B=4, N=256, D=32, H=512)
#define NB 4
#define NN 256
#define DD 32
#define HH 512

typedef __attribute__((ext_vector_type(8))) short short8;    // 8 bf16 (4 VGPRs) — MFMA A/B frag
typedef __attribute__((ext_vector_type(4))) float f32x4;     // 16x16 C/D frag
typedef __attribute__((ext_vector_type(16))) float f32x16;   // 32x32 C/D frag

// HW packed fp32->bf16 (RNE). a -> low 16, b -> high 16.
static __device__ __forceinline__ unsigned cvtpk(float a, float b) {
  unsigned r;
  asm("v_cvt_pk_bf16_f32 %0, %1, %2" : "=v"(r) : "v"(a), "v"(b));
  return r;
}
static __device__ __forceinline__ unsigned short f2bf1(float a) {
  return (unsigned short)(cvtpk(a, 0.f) & 0xffffu);
}

// build a bf16 A/B frag from 8 consecutive fp32 (two float4 loads already done)
static __device__ __forceinline__ short8 pack8(float4 a0, float4 a1) {
  union { unsigned u[4]; short8 s; } r;
  r.u[0] = cvtpk(a0.x, a0.y); r.u[1] = cvtpk(a0.z, a0.w);
  r.u[2] = cvtpk(a1.x, a1.y); r.u[3] = cvtpk(a1.z, a1.w);
  return r.s;
}

// T4-style barrier: drain ONLY LDS ops (the inter-wave communication path),
// keep global prefetch loads in flight across the barrier (proven R13:
// fused dropped below the top-5 dispatch threshold with VGPR unchanged).
#define BAR() do { asm volatile("s_waitcnt lgkmcnt(0)" ::: "memory"); \
                   __builtin_amdgcn_s_barrier(); } while (0)

// ---------------------------------------------------------------------------
// prep0 (grid 64x256): build W1F — W1 in bf16 B-fragment layout (see R4).
// ---------------------------------------------------------------------------
__global__ __launch_bounds__(256) void prep0(const float* __restrict__ W1,
                                             unsigned short* __restrict__ W1F) {
  const int f = blockIdx.x * 256 + threadIdx.x;   // 16384 threads, 4 rows each
  #pragma unroll
  for (int r = 0; r < 4; ++r) {
    int row = r * 16384 + f;
    int lane = row & 63;
    int nt = (row >> 6) & 7, w2 = (row >> 9) & 3, nblk = row >> 11;
    int quad = lane >> 4, l16 = lane & 15;
    int nl = w2 * 128 + l16 * 8 + nt;
    int hl = nl >> 5, c = nl & 31;
    const float* src = W1 + (size_t)(nblk * 16 + hl);
    float v[8];
    #pragma unroll
    for (int e = 0; e < 8; ++e)
      v[e] = src[(size_t)((quad * 8 + e) * 32 + c) * 512];
    uint4 p;
    p.x = cvtpk(v[0], v[1]); p.y = cvtpk(v[2], v[3]);
    p.z = cvtpk(v[4], v[5]); p.w = cvtpk(v[6], v[7]);
    *(uint4*)&W1F[(size_t)row * 8] = p;
  }
}

// ---------------------------------------------------------------------------
// prep1 (grid 641x256): T-GEMM from W1F / W2F builder / queue build / fill.
// (unchanged from R4 — proven)
// ---------------------------------------------------------------------------
__global__ __launch_bounds__(256) void prep1(const float* __restrict__ z,
                                             const unsigned short* __restrict__ W1F,
                                             const float* __restrict__ W2,
                                             const float* __restrict__ motif,
                                             unsigned short* __restrict__ W2F,
                                             unsigned short* __restrict__ Tall,
                                             int* __restrict__ jlist,
                                             int* __restrict__ jcnt,
                                             int* __restrict__ wq,
                                             int* __restrict__ wqn,
                                             float* __restrict__ out) {
  const int blk = blockIdx.x;
  const int tid = threadIdx.x;
  if (blk < 512) {
    const int nblk = blk >> 4, mgrp = blk & 15;
    const int bibase = mgrp * 64;
    const int w2 = tid >> 6, lane = tid & 63;
    const int quad = lane >> 4, l16 = lane & 15;

    short8 bfr[8];
    #pragma unroll
    for (int nt = 0; nt < 8; ++nt)
      bfr[nt] = *(const short8*)&W1F[(size_t)((((nblk * 4 + w2) * 8) + nt) * 64 + lane) * 8];

    const int ncol = nblk * 512 + w2 * 128 + l16 * 8;
    #pragma unroll
    for (int mtg = 0; mtg < 2; ++mtg) {
      short8 afr[2];
      #pragma unroll
      for (int mi = 0; mi < 2; ++mi) {
        const float* zr = z + (size_t)(bibase + (mtg * 2 + mi) * 16 + l16) * 32 + quad * 8;
        float4 a0 = *(const float4*)(zr);
        float4 a1 = *(const float4*)(zr + 4);
        afr[mi] = pack8(a0, a1);
      }
      f32x4 d[2][8];
      #pragma unroll
      for (int mi = 0; mi < 2; ++mi)
        #pragma unroll
        for (int nt = 0; nt < 8; ++nt)
          d[mi][nt] = __builtin_amdgcn_mfma_f32_16x16x32_bf16(
              afr[mi], bfr[nt], (f32x4){0.f, 0.f, 0.f, 0.f}, 0, 0, 0);
      #pragma unroll
      for (int mi = 0; mi < 2; ++mi)
        #pragma unroll
        for (int r = 0; r < 4; ++r) {
          int rowbi = bibase + (mtg * 2 + mi) * 16 + quad * 4 + r;
          if (motif[rowbi] != 0.f) {        // masked rows never read by fused
            uint4 p;
            p.x = cvtpk(d[mi][0][r], d[mi][1][r]);
            p.y = cvtpk(d[mi][2][r], d[mi][3][r]);
            p.z = cvtpk(d[mi][4][r], d[mi][5][r]);
            p.w = cvtpk(d[mi][6][r], d[mi][7][r]);
            *(uint4*)&Tall[(size_t)rowbi * 16384 + ncol] = p;
          }
        }
    }
  } else if (blk < 576) {
    int f8 = (blk - 512) * 256 + tid;       // frag-slot index (8 elems each)
    int lane = f8 & 63;
    int nt = (f8 >> 6) & 1, s = (f8 >> 7) & 3, hc = (f8 >> 9) & 7, w = (f8 >> 12) & 3;
    int k2 = w * 64 + nt * 32 + (lane & 31);
    int hb = hc * 64 + s * 16 + (lane >> 5) * 8;
    float v[8];
    #pragma unroll
    for (int e = 0; e < 8; ++e) v[e] = W2[(hb + e) * 256 + k2];
    uint4 p;
    p.x = cvtpk(v[0], v[1]); p.y = cvtpk(v[2], v[3]);
    p.z = cvtpk(v[4], v[5]); p.w = cvtpk(v[6], v[7]);
    ((uint4*)W2F)[f8] = p;
  } else if (blk == 576) {
    // ---- compaction + queue build: wave w handles batch b = w
    __shared__ int itemc[4];
    __shared__ int baseh[4];
    const int w = tid >> 6, lane = tid & 63;
    int cnt = 0;
    if (w < NB) {
      #pragma unroll
      for (int ch = 0; ch < 4; ++ch) {
        int j = ch * 64 + lane;
        float m = motif[w * 256 + j];
        bool alive = (m != 0.f);
        unsigned long long mk = __ballot(alive);
        unsigned long long below = mk & ((1ull << lane) - 1ull);
        int pos = __popcll(below);
        if (alive) jlist[w * 256 + cnt + pos] = j;
        cnt += __popcll(mk);
      }
      if (lane == 0) {
        jcnt[w] = cnt;
        itemc[w] = cnt * ((cnt + 63) >> 6);
      }
    }
    __syncthreads();
    if (tid == 0) {
      int s = 0;
      #pragma unroll
      for (int k = 0; k < NB; ++k) { baseh[k] = s; s += itemc[k]; }
      *wqn = s;
    }
    __syncthreads();
    if (w < NB) {
      const int K = (cnt + 63) >> 6;
      const int base = baseh[w];
      const int L2n = cnt * K;
      int rank = 0;
      #pragma unroll
      for (int ch = 0; ch < 4; ++ch) {
        int i = ch * 64 + lane;
        bool alive = (motif[w * 256 + i] != 0.f);
        unsigned long long mk = __ballot(alive);
        unsigned long long below = mk & ((1ull << lane) - 1ull);
        int pos = __popcll(below);
        if (alive) {
          int idx0 = (rank + pos) * K;
          for (int jt = 0; jt < K; ++jt) {
            int idx = idx0 + jt;
            int nidx = idx;
            // XCD pair-locality: place the two items of one bi 8 apart so
            // round-robin block->XCD puts them on the same XCD.
            if (K == 2) {
              int g = idx >> 4;
              if (g * 16 + 16 <= L2n)
                nidx = g * 16 + ((idx & 1) << 3) + ((idx >> 1) & 7);
            }
            wq[base + nidx] = (w * 256 + i) * 4 + jt;
          }
        }
        rank += __popcll(mk);
      }
    }
  } else {
    // ---- fill duty: constants for masked (bi,j) pairs; 64 blocks x 4096
    const size_t OUT2 = (size_t)NB * NN * NN;
    const int c = blk - 577;
    for (int p = c * 4096 + tid; p < (c + 1) * 4096; p += 256) {
      int bi = p >> 8, j = p & 255, b = bi >> 8;
      if (motif[bi] == 0.f || motif[b * 256 + j] == 0.f) {
        out[p] = 0.5f;
        out[OUT2 + p] = 0.f;
      }
    }
  }
}

// ---------------------------------------------------------------------------
// fused (round 14): R13 body (quarter ping-pong + BAR counted drains) with
// ONE change: all 8 tfr fragments hoisted to item start (R8's "one HBM
// round trip" trick, lost in the R10 quarter restructure). R13 loaded each
// phase's 2 tfr at the top of the consuming phase — a dependent global->
// MFMA chain (~200-900 cyc, Tall first-touch is HBM) exposed 5x per item.
// Hoisted loads are issued BEFORE the zfr/jlist pointer chase so they fly
// in its shadow. All tfr indices compile-time (full unroll) -> registers.
// Risk gate: VGPR_Count >= 160 or WRITE_SIZE > 5 MB => regalloc ballooned.
// ---------------------------------------------------------------------------
__global__ __launch_bounds__(256) void fused(const unsigned short* __restrict__ Tall,
                                             const unsigned short* __restrict__ W2F,
                                             const float* __restrict__ z,
                                             const float* __restrict__ b1,
                                             const float* __restrict__ b2,
                                             const float* __restrict__ W3,
                                             const float* __restrict__ b3,
                                             const float* __restrict__ motif,
                                             const int* __restrict__ jlist,
                                             const int* __restrict__ jcnt,
                                             const int* __restrict__ wq,
                                             const int* __restrict__ wqn,
                                             float* __restrict__ out) {
  __shared__ unsigned short h1s[2][64 * 136];  // ping-pong quarter buffers (34.8 KB)
  __shared__ float red[256];

  const int bx = blockIdx.x;
  const int tid = threadIdx.x;
  const size_t OUT2 = (size_t)NB * NN * NN;
  const int nq = *wqn;

  if (bx >= nq) return;                      // fill handled by prep1
  const int item = wq[bx];

  const int w = tid >> 6, lane = tid & 63;
  const int quad = lane >> 4, l16 = lane & 15;
  const int L = lane >> 5, c32 = lane & 31;

  const int bi = item >> 2, jt = item & 3;
  const int b = bi >> 8;
  const int cnt = jcnt[b];
  const int slotbase = jt * 64;
  const float mi_v = motif[bi];

  const unsigned short* Tbase = Tall + (size_t)bi * 16384 + (w * 16 + l16) * 32 + quad * 8;
  const unsigned short* Wp = W2F + w * 32768 + lane * 8;
  const float* b1base = b1 + w * 16 + quad * 4;

  // ---- ALL 8 tfr fragments issued up front: one Tall HBM round trip,
  //      overlapped with the bfp init and the zfr/jlist chase below.
  short8 tfr[8];
  #pragma unroll
  for (int q = 0; q < 8; ++q)
    tfr[q] = *(const short8*)(Tbase + q * 2048);

  // ---- hoisted B init: quarter-0 rows 0..7, in flight under startup
  short8 bfp[8][2];
  #pragma unroll
  for (int p = 0; p < 8; ++p) {
    bfp[p][0] = *(const short8*)(Wp + p * 1024);
    bfp[p][1] = *(const short8*)(Wp + p * 1024 + 512);
  }

  // phase-1 z frags gathered through jlist
  short8 zfr[4];
  #pragma unroll
  for (int sg = 0; sg < 4; ++sg) {
    int slot = slotbase + sg * 16 + l16;
    int sc = slot < cnt ? slot : cnt - 1;
    int jj = jlist[b * 256 + sc] & 255;
    const float* zr = z + (size_t)(b * 256 + jj) * 32 + quad * 8;
    float4 a0 = *(const float4*)(zr);
    float4 a1 = *(const float4*)(zr + 4);
    zfr[sg] = pack8(a0, a1);
  }

  // epilogue constants: this wave owns k2 in [64w, 64w+64)
  float b2v[2], w3v[2];
  #pragma unroll
  for (int nt = 0; nt < 2; ++nt) {
    int k2 = w * 64 + nt * 32 + c32;
    b2v[nt] = b2[k2];
    w3v[nt] = W3[k2];
  }

  f32x16 acc[2][2];
  #pragma unroll
  for (int mt = 0; mt < 2; ++mt)
    #pragma unroll
    for (int nt = 0; nt < 2; ++nt)
      acc[mt][nt] = (f32x16){0.f,0.f,0.f,0.f,0.f,0.f,0.f,0.f,
                             0.f,0.f,0.f,0.f,0.f,0.f,0.f,0.f};

  // ---- P1(quarter 0) -> buf0   (qq = 0,1)
  #pragma unroll
  for (int qq = 0; qq < 2; ++qq) {
    float4 b1f = *(const float4*)(b1base + qq * 64);
    f32x4 cin = {b1f.x, b1f.y, b1f.z, b1f.w};
    #pragma unroll
    for (int sg = 0; sg < 4; ++sg) {
      f32x4 d = __builtin_amdgcn_mfma_f32_16x16x32_bf16(tfr[qq], zfr[sg], cin, 0, 0, 0);
      uint2 p;
      p.x = cvtpk(fmaxf(d[0], 0.f), fmaxf(d[1], 0.f));
      p.y = cvtpk(fmaxf(d[2], 0.f), fmaxf(d[3], 0.f));
      *(uint2*)&h1s[0][(sg * 16 + l16) * 136 + qq * 64 + w * 16 + quad * 4] = p;
    }
  }
  BAR();

  // ---- 4 overlapped phases: P1(q+1) || P2(q)
  #pragma unroll
  for (int q = 0; q < 4; ++q) {
    // P1(q+1) -> buf[(q+1)&1]  (qq = 2q+2, 2q+3) — tfr from registers
    if (q < 3) {
      #pragma unroll
      for (int qi = 0; qi < 2; ++qi) {
        const int qq = 2 * q + 2 + qi;
        float4 b1f = *(const float4*)(b1base + qq * 64);
        f32x4 cin = {b1f.x, b1f.y, b1f.z, b1f.w};
        #pragma unroll
        for (int sg = 0; sg < 4; ++sg) {
          f32x4 d = __builtin_amdgcn_mfma_f32_16x16x32_bf16(tfr[qq], zfr[sg], cin, 0, 0, 0);
          uint2 p;
          p.x = cvtpk(fmaxf(d[0], 0.f), fmaxf(d[1], 0.f));
          p.y = cvtpk(fmaxf(d[2], 0.f), fmaxf(d[3], 0.f));
          *(uint2*)&h1s[(q + 1) & 1][(sg * 16 + l16) * 136 + qi * 64 + w * 16 + quad * 4] = p;
        }
      }
    }
    // P2(q) from buf[q&1]; consume bfp[u], prefetch next quarter's row u
    {
      const unsigned short* h1r = &h1s[q & 1][c32 * 136 + L * 8];
      short8 afp[2][2];
      afp[0][0] = *(const short8*)(h1r);
      afp[0][1] = *(const short8*)(h1r + 32 * 136);
      afp[1][0] = *(const short8*)(h1r + 16);
      afp[1][1] = *(const short8*)(h1r + 32 * 136 + 16);
      #pragma unroll
      for (int u = 0; u < 8; ++u) {
        const int cur = u & 1;
        short8 a0 = afp[cur][0], a1 = afp[cur][1];
        short8 b0 = bfp[u][0], b1q = bfp[u][1];
        if (u < 6) {
          afp[cur][0] = *(const short8*)(h1r + (u + 2) * 16);
          afp[cur][1] = *(const short8*)(h1r + 32 * 136 + (u + 2) * 16);
        }
        if (q < 3) {
          // next quarter nqt = q+1: half = nqt>>1, row = 8*(nqt&1)+u
          const unsigned short* Wn = Wp + ((q + 1) >> 1) * 16384
                                        + (8 * ((q + 1) & 1) + u) * 1024;
          bfp[u][0] = *(const short8*)(Wn);
          bfp[u][1] = *(const short8*)(Wn + 512);
        }
        acc[0][0] = __builtin_amdgcn_mfma_f32_32x32x16_bf16(a0, b0, acc[0][0], 0, 0, 0);
        acc[0][1] = __builtin_amdgcn_mfma_f32_32x32x16_bf16(a0, b1q, acc[0][1], 0, 0, 0);
        acc[1][0] = __builtin_amdgcn_mfma_f32_32x32x16_bf16(a1, b0, acc[1][0], 0, 0, 0);
        acc[1][1] = __builtin_amdgcn_mfma_f32_32x32x16_bf16(a1, b1q, acc[1][1], 0, 0, 0);
      }
    }
    // epilogue folded into the last phase (before its barrier)
    if (q == 3) {
      float pr[2][16];
      #pragma unroll
      for (int mt = 0; mt < 2; ++mt)
        #pragma unroll
        for (int reg = 0; reg < 16; ++reg) {
          float s = 0.f;
          #pragma unroll
          for (int nt = 0; nt < 2; ++nt) {
            float v = acc[mt][nt][reg] + b2v[nt];
            v = v > 0.f ? v : 0.f;
            s += v * w3v[nt];
          }
          s += __shfl_xor(s, 1);
          s += __shfl_xor(s, 2);
          s += __shfl_xor(s, 4);
          s += __shfl_xor(s, 8);
          s += __shfl_xor(s, 16);
          pr[mt][reg] = s;
        }
      if (c32 == 0) {
        #pragma unroll
        for (int mt = 0; mt < 2; ++mt)
          #pragma unroll
          for (int g = 0; g < 4; ++g) {
            float4 vv = {pr[mt][g * 4 + 0], pr[mt][g * 4 + 1],
                         pr[mt][g * 4 + 2], pr[mt][g * 4 + 3]};
            *(float4*)&red[w * 64 + mt * 32 + g * 8 + L * 4] = vv;
          }
      }
    }
    BAR();
  }

  // ---- readout
  if (tid < 64) {
    int slot = slotbase + tid;
    if (slot < cnt) {
      int j = jlist[b * 256 + slot] & 255;
      float logit = red[tid] + red[64 + tid] + red[128 + tid] + red[192 + tid] + b3[0];
      float mm = mi_v * motif[b * 256 + j];
      logit *= mm;
      float map = 1.f / (1.f + expf(-logit));
      size_t idx = (size_t)bi * 256 + j;
      out[idx] = map;
      out[OUT2 + idx] = logit;
    }
  }
}

// ---------------------------------------------------------------------------
extern "C" void kernel_launch(void* const* d_in, const int* in_sizes, int n_in,
                              void* d_out, int out_size, void* d_ws, size_t ws_size,
                              hipStream_t stream) {
  const float* z     = (const float*)d_in[0];
  const float* motif = (const float*)d_in[1];
  // d_in[2] residue_mask: all-ones, unused by the reference computation
  const float* W1 = (const float*)d_in[3];
  const float* b1 = (const float*)d_in[4];
  const float* W2 = (const float*)d_in[5];
  const float* b2 = (const float*)d_in[6];
  const float* W3 = (const float*)d_in[7];
  const float* b3 = (const float*)d_in[8];
  float* out = (float*)d_out;

  char* ws = (char*)d_ws;
  unsigned short* Tall = (unsigned short*)ws;                            // 32 MiB
  unsigned short* W2F  = (unsigned short*)(ws + 33554432);               // 256 KiB
  unsigned short* W1F  = (unsigned short*)(ws + 33554432 + 262144);      // 1 MiB
  char* tail = ws + 33554432 + 262144 + 1048576;
  int* jlist = (int*)(tail);                                             // 4 KiB
  int* jcnt  = (int*)(tail + 4096);                                      // 64 B
  int* wq    = (int*)(tail + 4096 + 64);                                 // 16 KiB
  int* wqn   = (int*)(tail + 4096 + 64 + 16384);                         // 64 B

  prep0<<<64, 256, 0, stream>>>(W1, W1F);
  prep1<<<641, 256, 0, stream>>>(z, W1F, W2, motif, W2F, Tall,
                                 jlist, jcnt, wq, wqn, out);
  fused<<<4096, 256, 0, stream>>>(Tall, W2F, z, b1, b2, W3, b3, motif,
                                  jlist, jcnt, wq, wqn, out);
}